// Round 7
// baseline (162.002 us; speedup 1.0000x reference)
//
#include <hip/hip_runtime.h>
#include <stdint.h>

#define B 1024
#define F 256
#define D 64

typedef __attribute__((ext_vector_type(8))) short short8;
typedef __attribute__((ext_vector_type(4))) float f32x4;

__device__ __forceinline__ short f2bf(float f) {
    unsigned u = __builtin_bit_cast(unsigned, f);
    u += 0x7fff + ((u >> 16) & 1);   // RNE
    return (short)(u >> 16);
}
__device__ __forceinline__ float bf2f(short s) {
    unsigned u = ((unsigned)(unsigned short)s) << 16;
    return __builtin_bit_cast(float, u);
}
// pack two f32 -> two bf16 (round-half-up), 3 VALU
__device__ __forceinline__ unsigned pk_bf16(float a, float b) {
    unsigned ua = __builtin_bit_cast(unsigned, a) + 0x8000u;
    unsigned ub = __builtin_bit_cast(unsigned, b) + 0x8000u;
    return __builtin_amdgcn_perm(ub, ua, 0x07060302u);  // [bf16(a) | bf16(b)<<16]
}

__device__ __forceinline__ float dot4(float4 a, float4 b) {
    return a.x * b.x + a.y * b.y + a.z * b.z + a.w * b.w;
}

// ---------------------------------------------------------------------------
// Workspace layout:
//   trans : 2*F*D f32
//   qkv   : 3*F*D f32
//   gS    : B*F   f32     (s0*s2 row scale, per batch)
//   At    : [F/32][F][32] bf16   (gate*cross, K-tiled)      = 128 KB
//   q2K   : [F/32][64][32] bf16  (qkv2^T, K-tiled, d-PERMUTED: physical slot
//                                 p=(d&3)*16+(d>>2) so fragment nt at lane l16
//                                 holds logical col l16*4+nt -> float4 stores)
//   s1S   : B*F   bf16    (s1 column scale, per batch)
// ---------------------------------------------------------------------------

// Kernel A: trans/qkv = indicator @ W
__global__ void precompute_trans(const float* __restrict__ indicator,
                                 const float* __restrict__ W_qk,
                                 const float* __restrict__ W_qkv,
                                 float* __restrict__ trans,
                                 float* __restrict__ qkv) {
    int idx = blockIdx.x * blockDim.x + threadIdx.x;   // 0 .. 5*F*D
    int n   = idx / (F * D);
    int rem = idx - n * (F * D);
    int f   = rem / D;
    int e   = rem - f * D;
    const float* W = (n < 2) ? (W_qk + n * D * D) : (W_qkv + (n - 2) * D * D);
    const float* ind = indicator + f * D;
    float acc = 0.f;
#pragma unroll 8
    for (int d = 0; d < D; ++d) acc += ind[d] * W[d * D + e];
    if (n < 2) trans[n * F * D + f * D + e] = acc;
    else       qkv[(n - 2) * F * D + f * D + e] = acc;
}

// Merged kernel (256 threads):
//   blocks [0, B/2)        -> compute_s for 2 batches, ONE f-row PER THREAD:
//       no shuffles, no LDS; thread f serially accumulates its 64-elem dots
//       over 16 float4 chunks. Lane stride is 256B but consecutive chunks
//       reuse the same cache lines (4KB/wave working set, L1-resident) ->
//       dense-strided full-BW streaming of the 64MB feature tensor.
//   blocks [B/2, B/2 + F)  -> compute_Mt column j (unchanged from r5)
__global__ __launch_bounds__(256) void s_and_Mt(const float* __restrict__ feature,
                                                const float* __restrict__ trans,
                                                const float* __restrict__ qkv,
                                                float* __restrict__ gS,
                                                short* __restrict__ s1S,
                                                short* __restrict__ At,
                                                short* __restrict__ q2K) {
    int blk = blockIdx.x;
    int tid = threadIdx.x;
    if (blk < B / 2) {
        int b0 = blk * 2;
        int f  = tid;                        // one f-row per thread
        const float4* fp0 = (const float4*)(feature + ((size_t)(b0 * F + f)) * D);
        const float4* fp1 = (const float4*)(feature + ((size_t)((b0 + 1) * F + f)) * D);
        const float4* qp0 = (const float4*)(qkv + f * D);
        const float4* qp1 = (const float4*)(qkv + F * D + f * D);
        const float4* qp2 = (const float4*)(qkv + 2 * F * D + f * D);
        float a00 = 0.f, a01 = 0.f, a02 = 0.f;
        float a10 = 0.f, a11 = 0.f, a12 = 0.f;
#pragma unroll
        for (int c = 0; c < D / 4; ++c) {
            float4 q0 = qp0[c], q1 = qp1[c], q2 = qp2[c];
            float4 f0 = fp0[c], f1 = fp1[c];
            a00 += dot4(f0, q0);
            a01 += dot4(f0, q1);
            a02 += dot4(f0, q2);
            a10 += dot4(f1, q0);
            a11 += dot4(f1, q1);
            a12 += dot4(f1, q2);
        }
        gS[b0 * F + f]        = a00 * a02;
        gS[(b0 + 1) * F + f]  = a10 * a12;
        s1S[b0 * F + f]       = f2bf(a01);
        s1S[(b0 + 1) * F + f] = f2bf(a11);
    } else {
        // ---- compute_Mt: At[(j>>5)][i][j&31] = gate(i,j) ? qkv1[i].qkv0[j] : 0
        //      q2K[(i>>5)][p(j)][i&31] = qkv2[i][j], p(j)=(j&3)*16+(j>>2) ----
        int j = blk - B / 2;   // F columns
        int i = tid;           // F threads
        const float4* t0 = (const float4*)(trans + i * D);
        const float4* t1 = (const float4*)(trans + F * D + j * D);
        const float4* q1 = (const float4*)(qkv + F * D + i * D);
        const float4* q0 = (const float4*)(qkv + j * D);
        float d0 = 0.f, d1 = 0.f;
#pragma unroll
        for (int k = 0; k < D / 4; ++k) {
            float4 a = t0[k], b = t1[k], c = q1[k], e = q0[k];
            d0 += dot4(a, b);
            d1 += dot4(c, e);
        }
        float v = (d0 > 0.f) ? d1 : 0.f;
        At[((j >> 5) * F + i) * 32 + (j & 31)] = f2bf(v);
        if (j < D) {
            int p = (j & 3) * 16 + (j >> 2);   // d-permutation for float4 stores
            q2K[((i >> 5) * D + p) * 32 + (i & 31)] = f2bf(qkv[2 * F * D + i * D + j]);
        }
    }
}

// Kernel G (round-5 bf16 version, known-good): 
// out[b,i,d] = gS[b,i] * sum_j At[i,j] * s1[b,j] * q2[j,d]
// Block = (batch-group of 8, i-tile of 64 rows); 512 threads / 8 waves.
// At i-slice (32 KB) + q2K (32 KB) staged ONCE into LDS.
// B-fragment nt at lane l16 holds logical d-col l16*4+nt (via q2K permutation)
// -> epilogue is float4 (dwordx4) stores, 16 B/lane.
__global__ __launch_bounds__(512, 4) void gemm_out(const short* __restrict__ At,
                                                   const short* __restrict__ q2K,
                                                   const float* __restrict__ gS,
                                                   const short* __restrict__ s1S,
                                                   float* __restrict__ out) {
    int it  = blockIdx.x & 3;        // i-tile: rows [it*64, it*64+64)
    int bg  = blockIdx.x >> 2;       // batch-group of 8
    int tid = threadIdx.x;

    __shared__ __align__(16) short AtL[8 * 64 * 32];   // 32 KB: [jt][row 0..63][32]
    __shared__ __align__(16) short q2L[8 * 64 * 32];   // 32 KB: [jt][slot 0..63][32]

    // ---- stage At i-slice + q2K into LDS (coalesced float4 copies) ----
    {
        const float4* Ag = (const float4*)At;
        const float4* Qg = (const float4*)q2K;
        float4* Al = (float4*)AtL;
        float4* Ql = (float4*)q2L;
#pragma unroll
        for (int v = tid; v < 2048; v += 512) {
            int jt = v >> 8, k = v & 255;                 // 256 float4 per jt-chunk
            Al[v] = Ag[jt * 1024 + it * 256 + k];         // global chunk stride = 1024 f4
        }
#pragma unroll
        for (int v = tid; v < 2048; v += 512) Ql[v] = Qg[v];
    }
    __syncthreads();

    int w    = tid >> 6;        // wave -> batch
    int lane = tid & 63;
    int l16  = lane & 15;
    int lq   = lane >> 4;
    int kq   = lq * 8;
    int b    = bg * 8 + w;

    const short* s1b = s1S + b * F;

    f32x4 acc[4][4];
#pragma unroll
    for (int mt = 0; mt < 4; ++mt)
#pragma unroll
        for (int nt = 0; nt < 4; ++nt) acc[mt][nt] = (f32x4){0.f, 0.f, 0.f, 0.f};

    for (int jt = 0; jt < F / 32; ++jt) {
        // s1 fragment (broadcast within 16-lane groups): 8 bf16 -> f32
        short8 sv = *(const short8*)(s1b + jt * 32 + kq);
        float sf[8];
#pragma unroll
        for (int e = 0; e < 8; ++e) sf[e] = bf2f(sv[e]);

        // B fragments from LDS: q2 physical slot nt*16+l16 (logical d=l16*4+nt),
        // scaled by s1, packed bf16
        short8 bfr[4];
#pragma unroll
        for (int nt = 0; nt < 4; ++nt) {
            int d = nt * 16 + l16;
            short8 qv = *(const short8*)(q2L + (jt * 64 + d) * 32 + kq);
            int4 packed;
            packed.x = pk_bf16(bf2f(qv[0]) * sf[0], bf2f(qv[1]) * sf[1]);
            packed.y = pk_bf16(bf2f(qv[2]) * sf[2], bf2f(qv[3]) * sf[3]);
            packed.z = pk_bf16(bf2f(qv[4]) * sf[4], bf2f(qv[5]) * sf[5]);
            packed.w = pk_bf16(bf2f(qv[6]) * sf[6], bf2f(qv[7]) * sf[7]);
            bfr[nt] = __builtin_bit_cast(short8, packed);
        }
        // A fragments from LDS + MFMA over the 64-row i-tile
#pragma unroll
        for (int mt = 0; mt < 4; ++mt) {
            short8 af = *(const short8*)(AtL + (jt * 64 + mt * 16 + l16) * 32 + kq);
#pragma unroll
            for (int nt = 0; nt < 4; ++nt)
                acc[mt][nt] = __builtin_amdgcn_mfma_f32_16x16x32_bf16(
                    af, bfr[nt], acc[mt][nt], 0, 0, 0);
        }
    }

    // ---- epilogue: gS row scale + float4 stores (cols l16*4 .. l16*4+3) ----
    const float4* g4 = (const float4*)(gS + b * F + it * 64);
#pragma unroll
    for (int mt = 0; mt < 4; ++mt) {
        float4 gg = g4[mt * 4 + lq];   // rows it*64 + mt*16 + lq*4 .. +3
        float* obase = out + ((size_t)(b * F + it * 64 + mt * 16 + lq * 4)) * D + l16 * 4;
        float4 v0 = {gg.x * acc[mt][0][0], gg.x * acc[mt][1][0],
                     gg.x * acc[mt][2][0], gg.x * acc[mt][3][0]};
        float4 v1 = {gg.y * acc[mt][0][1], gg.y * acc[mt][1][1],
                     gg.y * acc[mt][2][1], gg.y * acc[mt][3][1]};
        float4 v2 = {gg.z * acc[mt][0][2], gg.z * acc[mt][1][2],
                     gg.z * acc[mt][2][2], gg.z * acc[mt][3][2]};
        float4 v3 = {gg.w * acc[mt][0][3], gg.w * acc[mt][1][3],
                     gg.w * acc[mt][2][3], gg.w * acc[mt][3][3]};
        *(float4*)(obase + 0 * D) = v0;
        *(float4*)(obase + 1 * D) = v1;
        *(float4*)(obase + 2 * D) = v2;
        *(float4*)(obase + 3 * D) = v3;
    }
}

extern "C" void kernel_launch(void* const* d_in, const int* in_sizes, int n_in,
                              void* d_out, int out_size, void* d_ws, size_t ws_size,
                              hipStream_t stream) {
    const float* feature   = (const float*)d_in[0];
    const float* indicator = (const float*)d_in[1];
    const float* W_qk      = (const float*)d_in[2];
    const float* W_qkv     = (const float*)d_in[3];
    float* out = (float*)d_out;

    float* ws    = (float*)d_ws;
    float* trans = ws;                        // 2*F*D f32
    float* qkv   = trans + 2 * F * D;         // 3*F*D f32
    float* gS    = qkv + 3 * F * D;           // B*F f32
    short* At    = (short*)(gS + B * F);      // F*F bf16 (K-tiled)
    short* q2K   = At + F * F;                // (F/32)*64*32 bf16 (K-tiled, permuted)
    short* s1S   = q2K + (F / 32) * D * 32;   // B*F bf16

    hipLaunchKernelGGL(precompute_trans, dim3((5 * F * D) / 256), dim3(256), 0,
                       stream, indicator, W_qk, W_qkv, trans, qkv);
    hipLaunchKernelGGL(s_and_Mt, dim3(B / 2 + F), dim3(256), 0, stream,
                       feature, trans, qkv, gS, s1S, At, q2K);
    hipLaunchKernelGGL(gemm_out, dim3((B / 8) * 4), dim3(512), 0, stream,
                       At, q2K, gS, s1S, out);
}

// Round 8
// 145.346 us; speedup vs baseline: 1.1146x; 1.1146x over previous
//
#include <hip/hip_runtime.h>
#include <stdint.h>

#define B 1024
#define F 256
#define D 64

typedef __attribute__((ext_vector_type(8))) short short8;
typedef __attribute__((ext_vector_type(4))) float f32x4;

__device__ __forceinline__ short f2bf(float f) {
    unsigned u = __builtin_bit_cast(unsigned, f);
    u += 0x7fff + ((u >> 16) & 1);   // RNE
    return (short)(u >> 16);
}
__device__ __forceinline__ float bf2f(short s) {
    unsigned u = ((unsigned)(unsigned short)s) << 16;
    return __builtin_bit_cast(float, u);
}
// pack two f32 -> two bf16 (round-half-up), 3 VALU
__device__ __forceinline__ unsigned pk_bf16(float a, float b) {
    unsigned ua = __builtin_bit_cast(unsigned, a) + 0x8000u;
    unsigned ub = __builtin_bit_cast(unsigned, b) + 0x8000u;
    return __builtin_amdgcn_perm(ub, ua, 0x07060302u);  // [bf16(a) | bf16(b)<<16]
}

__device__ __forceinline__ float dot4(float4 a, float4 b) {
    return a.x * b.x + a.y * b.y + a.z * b.z + a.w * b.w;
}

// ---------------------------------------------------------------------------
// Workspace layout:
//   trans : 2*F*D f32
//   qkv   : 3*F*D f32
//   gS    : B*F   f32     (s0*s2 row scale, per batch)
//   At    : [F/32][F][32] bf16   (gate*cross, K-tiled)      = 128 KB
//   q2K   : [F/32][64][32] bf16  (qkv2^T, K-tiled, d-PERMUTED: physical slot
//                                 p=(d&3)*16+(d>>2) so fragment nt at lane l16
//                                 holds logical col l16*4+nt -> float4 stores)
//   s1S   : B*F   bf16    (s1 column scale, per batch)
// ---------------------------------------------------------------------------

// Kernel A: trans/qkv = indicator @ W
__global__ void precompute_trans(const float* __restrict__ indicator,
                                 const float* __restrict__ W_qk,
                                 const float* __restrict__ W_qkv,
                                 float* __restrict__ trans,
                                 float* __restrict__ qkv) {
    int idx = blockIdx.x * blockDim.x + threadIdx.x;   // 0 .. 5*F*D
    int n   = idx / (F * D);
    int rem = idx - n * (F * D);
    int f   = rem / D;
    int e   = rem - f * D;
    const float* W = (n < 2) ? (W_qk + n * D * D) : (W_qkv + (n - 2) * D * D);
    const float* ind = indicator + f * D;
    float acc = 0.f;
#pragma unroll 8
    for (int d = 0; d < D; ++d) acc += ind[d] * W[d * D + e];
    if (n < 2) trans[n * F * D + f * D + e] = acc;
    else       qkv[(n - 2) * F * D + f * D + e] = acc;
}

// Merged kernel (256 threads):
//   blocks [0, B/2)       -> compute_s for 2 batches, 4 LANES PER f-ROW:
//       lane l of a 4-lane group reads chunk k=l+4t (t=0..3): each wave load
//       is 16 fully-consumed 64B line segments (100% line density), reuse
//       window 20 KB < L1. Reduction = 2 butterfly steps x 6 vals = 12
//       shuffles per 96 FMAs (8x less DS-pipe pressure than 16-lane reduce;
//       fixes round-7's 256B-stride L1 thrash AND round-5's shuffle bound).
//   blocks [B/2, B/2 + F) -> compute_Mt column j (unchanged, round-5 proven)
__global__ __launch_bounds__(256) void s_and_Mt(const float* __restrict__ feature,
                                                const float* __restrict__ trans,
                                                const float* __restrict__ qkv,
                                                float* __restrict__ gS,
                                                short* __restrict__ s1S,
                                                short* __restrict__ At,
                                                short* __restrict__ q2K) {
    int blk = blockIdx.x;
    int tid = threadIdx.x;
    if (blk < B / 2) {
        int b0 = blk * 2;
        int r  = tid >> 2;    // f-row group, 0..63
        int l  = tid & 3;     // lane-in-row
#pragma unroll
        for (int p = 0; p < 4; ++p) {
            int f = p * 64 + r;
            const float4* fp0 = (const float4*)(feature + ((size_t)(b0 * F + f)) * D);
            const float4* fp1 = (const float4*)(feature + ((size_t)((b0 + 1) * F + f)) * D);
            const float4* qp0 = (const float4*)(qkv + f * D);
            const float4* qp1 = (const float4*)(qkv + F * D + f * D);
            const float4* qp2 = (const float4*)(qkv + 2 * F * D + f * D);
            float a00 = 0.f, a01 = 0.f, a02 = 0.f;
            float a10 = 0.f, a11 = 0.f, a12 = 0.f;
#pragma unroll
            for (int t = 0; t < 4; ++t) {
                int k = l + 4 * t;   // adjacent lanes -> adjacent float4
                float4 q0 = qp0[k], q1 = qp1[k], q2 = qp2[k];
                float4 f0 = fp0[k], f1 = fp1[k];
                a00 += dot4(f0, q0);
                a01 += dot4(f0, q1);
                a02 += dot4(f0, q2);
                a10 += dot4(f1, q0);
                a11 += dot4(f1, q1);
                a12 += dot4(f1, q2);
            }
#pragma unroll
            for (int m = 1; m < 4; m <<= 1) {
                a00 += __shfl_xor(a00, m, 64);
                a01 += __shfl_xor(a01, m, 64);
                a02 += __shfl_xor(a02, m, 64);
                a10 += __shfl_xor(a10, m, 64);
                a11 += __shfl_xor(a11, m, 64);
                a12 += __shfl_xor(a12, m, 64);
            }
            if (l == 0) {
                gS[b0 * F + f]        = a00 * a02;
                gS[(b0 + 1) * F + f]  = a10 * a12;
                s1S[b0 * F + f]       = f2bf(a01);
                s1S[(b0 + 1) * F + f] = f2bf(a11);
            }
        }
    } else {
        // ---- compute_Mt: At[(j>>5)][i][j&31] = gate(i,j) ? qkv1[i].qkv0[j] : 0
        //      q2K[(i>>5)][p(j)][i&31] = qkv2[i][j], p(j)=(j&3)*16+(j>>2) ----
        int j = blk - B / 2;   // F columns
        int i = tid;           // F threads
        const float4* t0 = (const float4*)(trans + i * D);
        const float4* t1 = (const float4*)(trans + F * D + j * D);
        const float4* q1 = (const float4*)(qkv + F * D + i * D);
        const float4* q0 = (const float4*)(qkv + j * D);
        float d0 = 0.f, d1 = 0.f;
#pragma unroll
        for (int k = 0; k < D / 4; ++k) {
            float4 a = t0[k], b = t1[k], c = q1[k], e = q0[k];
            d0 += dot4(a, b);
            d1 += dot4(c, e);
        }
        float v = (d0 > 0.f) ? d1 : 0.f;
        At[((j >> 5) * F + i) * 32 + (j & 31)] = f2bf(v);
        if (j < D) {
            int p = (j & 3) * 16 + (j >> 2);   // d-permutation for float4 stores
            q2K[((i >> 5) * D + p) * 32 + (i & 31)] = f2bf(qkv[2 * F * D + i * D + j]);
        }
    }
}

// Kernel G (round-5 bf16 version, known-good):
// out[b,i,d] = gS[b,i] * sum_j At[i,j] * s1[b,j] * q2[j,d]
// Block = (batch-group of 8, i-tile of 64 rows); 512 threads / 8 waves.
// At i-slice (32 KB) + q2K (32 KB) staged ONCE into LDS.
// B-fragment nt at lane l16 holds logical d-col l16*4+nt (via q2K permutation)
// -> epilogue is float4 (dwordx4) stores, 16 B/lane.
__global__ __launch_bounds__(512, 4) void gemm_out(const short* __restrict__ At,
                                                   const short* __restrict__ q2K,
                                                   const float* __restrict__ gS,
                                                   const short* __restrict__ s1S,
                                                   float* __restrict__ out) {
    int it  = blockIdx.x & 3;        // i-tile: rows [it*64, it*64+64)
    int bg  = blockIdx.x >> 2;       // batch-group of 8
    int tid = threadIdx.x;

    __shared__ __align__(16) short AtL[8 * 64 * 32];   // 32 KB: [jt][row 0..63][32]
    __shared__ __align__(16) short q2L[8 * 64 * 32];   // 32 KB: [jt][slot 0..63][32]

    // ---- stage At i-slice + q2K into LDS (coalesced float4 copies) ----
    {
        const float4* Ag = (const float4*)At;
        const float4* Qg = (const float4*)q2K;
        float4* Al = (float4*)AtL;
        float4* Ql = (float4*)q2L;
#pragma unroll
        for (int v = tid; v < 2048; v += 512) {
            int jt = v >> 8, k = v & 255;                 // 256 float4 per jt-chunk
            Al[v] = Ag[jt * 1024 + it * 256 + k];         // global chunk stride = 1024 f4
        }
#pragma unroll
        for (int v = tid; v < 2048; v += 512) Ql[v] = Qg[v];
    }
    __syncthreads();

    int w    = tid >> 6;        // wave -> batch
    int lane = tid & 63;
    int l16  = lane & 15;
    int lq   = lane >> 4;
    int kq   = lq * 8;
    int b    = bg * 8 + w;

    const short* s1b = s1S + b * F;

    f32x4 acc[4][4];
#pragma unroll
    for (int mt = 0; mt < 4; ++mt)
#pragma unroll
        for (int nt = 0; nt < 4; ++nt) acc[mt][nt] = (f32x4){0.f, 0.f, 0.f, 0.f};

    for (int jt = 0; jt < F / 32; ++jt) {
        // s1 fragment (broadcast within 16-lane groups): 8 bf16 -> f32
        short8 sv = *(const short8*)(s1b + jt * 32 + kq);
        float sf[8];
#pragma unroll
        for (int e = 0; e < 8; ++e) sf[e] = bf2f(sv[e]);

        // B fragments from LDS: q2 physical slot nt*16+l16 (logical d=l16*4+nt),
        // scaled by s1, packed bf16
        short8 bfr[4];
#pragma unroll
        for (int nt = 0; nt < 4; ++nt) {
            int d = nt * 16 + l16;
            short8 qv = *(const short8*)(q2L + (jt * 64 + d) * 32 + kq);
            int4 packed;
            packed.x = pk_bf16(bf2f(qv[0]) * sf[0], bf2f(qv[1]) * sf[1]);
            packed.y = pk_bf16(bf2f(qv[2]) * sf[2], bf2f(qv[3]) * sf[3]);
            packed.z = pk_bf16(bf2f(qv[4]) * sf[4], bf2f(qv[5]) * sf[5]);
            packed.w = pk_bf16(bf2f(qv[6]) * sf[6], bf2f(qv[7]) * sf[7]);
            bfr[nt] = __builtin_bit_cast(short8, packed);
        }
        // A fragments from LDS + MFMA over the 64-row i-tile
#pragma unroll
        for (int mt = 0; mt < 4; ++mt) {
            short8 af = *(const short8*)(AtL + (jt * 64 + mt * 16 + l16) * 32 + kq);
#pragma unroll
            for (int nt = 0; nt < 4; ++nt)
                acc[mt][nt] = __builtin_amdgcn_mfma_f32_16x16x32_bf16(
                    af, bfr[nt], acc[mt][nt], 0, 0, 0);
        }
    }

    // ---- epilogue: gS row scale + float4 stores (cols l16*4 .. l16*4+3) ----
    const float4* g4 = (const float4*)(gS + b * F + it * 64);
#pragma unroll
    for (int mt = 0; mt < 4; ++mt) {
        float4 gg = g4[mt * 4 + lq];   // rows it*64 + mt*16 + lq*4 .. +3
        float* obase = out + ((size_t)(b * F + it * 64 + mt * 16 + lq * 4)) * D + l16 * 4;
        float4 v0 = {gg.x * acc[mt][0][0], gg.x * acc[mt][1][0],
                     gg.x * acc[mt][2][0], gg.x * acc[mt][3][0]};
        float4 v1 = {gg.y * acc[mt][0][1], gg.y * acc[mt][1][1],
                     gg.y * acc[mt][2][1], gg.y * acc[mt][3][1]};
        float4 v2 = {gg.z * acc[mt][0][2], gg.z * acc[mt][1][2],
                     gg.z * acc[mt][2][2], gg.z * acc[mt][3][2]};
        float4 v3 = {gg.w * acc[mt][0][3], gg.w * acc[mt][1][3],
                     gg.w * acc[mt][2][3], gg.w * acc[mt][3][3]};
        *(float4*)(obase + 0 * D) = v0;
        *(float4*)(obase + 1 * D) = v1;
        *(float4*)(obase + 2 * D) = v2;
        *(float4*)(obase + 3 * D) = v3;
    }
}

extern "C" void kernel_launch(void* const* d_in, const int* in_sizes, int n_in,
                              void* d_out, int out_size, void* d_ws, size_t ws_size,
                              hipStream_t stream) {
    const float* feature   = (const float*)d_in[0];
    const float* indicator = (const float*)d_in[1];
    const float* W_qk      = (const float*)d_in[2];
    const float* W_qkv     = (const float*)d_in[3];
    float* out = (float*)d_out;

    float* ws    = (float*)d_ws;
    float* trans = ws;                        // 2*F*D f32
    float* qkv   = trans + 2 * F * D;         // 3*F*D f32
    float* gS    = qkv + 3 * F * D;           // B*F f32
    short* At    = (short*)(gS + B * F);      // F*F bf16 (K-tiled)
    short* q2K   = At + F * F;                // (F/32)*64*32 bf16 (K-tiled, permuted)
    short* s1S   = q2K + (F / 32) * D * 32;   // B*F bf16

    hipLaunchKernelGGL(precompute_trans, dim3((5 * F * D) / 256), dim3(256), 0,
                       stream, indicator, W_qk, W_qkv, trans, qkv);
    hipLaunchKernelGGL(s_and_Mt, dim3(B / 2 + F), dim3(256), 0, stream,
                       feature, trans, qkv, gS, s1S, At, q2K);
    hipLaunchKernelGGL(gemm_out, dim3((B / 8) * 4), dim3(512), 0, stream,
                       At, q2K, gS, s1S, out);
}

// Round 9
// 142.558 us; speedup vs baseline: 1.1364x; 1.0196x over previous
//
#include <hip/hip_runtime.h>
#include <stdint.h>

#define B 1024
#define F 256
#define D 64

typedef __attribute__((ext_vector_type(8))) short short8;
typedef __attribute__((ext_vector_type(4))) float f32x4;

__device__ __forceinline__ short f2bf(float f) {
    unsigned u = __builtin_bit_cast(unsigned, f);
    u += 0x7fff + ((u >> 16) & 1);   // RNE
    return (short)(u >> 16);
}
__device__ __forceinline__ float bf2f(short s) {
    unsigned u = ((unsigned)(unsigned short)s) << 16;
    return __builtin_bit_cast(float, u);
}
// pack two f32 -> two bf16 (round-half-up), 3 VALU
__device__ __forceinline__ unsigned pk_bf16(float a, float b) {
    unsigned ua = __builtin_bit_cast(unsigned, a) + 0x8000u;
    unsigned ub = __builtin_bit_cast(unsigned, b) + 0x8000u;
    return __builtin_amdgcn_perm(ub, ua, 0x07060302u);  // [bf16(a) | bf16(b)<<16]
}

__device__ __forceinline__ float dot4(float4 a, float4 b) {
    return a.x * b.x + a.y * b.y + a.z * b.z + a.w * b.w;
}

// ---------------------------------------------------------------------------
// Workspace layout:
//   trans : 2*F*D f32
//   qkv   : 3*F*D f32
//   gS    : B*F   f32     (s0*s2 row scale, per batch)
//   At    : [F/32][F][32] bf16   (gate*cross, K-tiled)      = 128 KB
//   q2K   : [F/32][64][32] bf16  (qkv2^T, K-tiled, d-PERMUTED: physical slot
//                                 p=(d&3)*16+(d>>2) so fragment nt at lane l16
//                                 holds logical col l16*4+nt -> float4 stores)
//   s1S   : B*F   bf16    (s1 column scale, per batch)
// ---------------------------------------------------------------------------

// Kernel A: trans/qkv = indicator @ W
__global__ void precompute_trans(const float* __restrict__ indicator,
                                 const float* __restrict__ W_qk,
                                 const float* __restrict__ W_qkv,
                                 float* __restrict__ trans,
                                 float* __restrict__ qkv) {
    int idx = blockIdx.x * blockDim.x + threadIdx.x;   // 0 .. 5*F*D
    int n   = idx / (F * D);
    int rem = idx - n * (F * D);
    int f   = rem / D;
    int e   = rem - f * D;
    const float* W = (n < 2) ? (W_qk + n * D * D) : (W_qkv + (n - 2) * D * D);
    const float* ind = indicator + f * D;
    float acc = 0.f;
#pragma unroll 8
    for (int d = 0; d < D; ++d) acc += ind[d] * W[d * D + e];
    if (n < 2) trans[n * F * D + f * D + e] = acc;
    else       qkv[(n - 2) * F * D + f * D + e] = acc;
}

// Merged kernel, OCCUPANCY-TUNED: __launch_bounds__(256, 8) caps VGPR<=64 ->
// 8 blocks/CU = 32 waves/CU (was 12). The s-stream is latency-bound HBM read
// (R5-R8 evidence: 12 w/CU -> 1.5 TB/s, 16 w/CU -> 1.8; fills at 32 w/CU hit
// 6.4 TB/s), so double the resident waves and halve per-block work:
//   blocks [0, B)        -> s for HALF the rows (128) of 2 batches:
//       blk>>1 = batch pair, blk&1 = row half. 16 lanes/row (R5 coalescing).
//   blocks [B, B + F)    -> compute_Mt column j (round-5 proven)
__global__ __launch_bounds__(256, 8) void s_and_Mt(const float* __restrict__ feature,
                                                   const float* __restrict__ trans,
                                                   const float* __restrict__ qkv,
                                                   float* __restrict__ gS,
                                                   short* __restrict__ s1S,
                                                   short* __restrict__ At,
                                                   short* __restrict__ q2K) {
    int blk = blockIdx.x;
    int tid = threadIdx.x;
    if (blk < B) {
        int b0   = (blk >> 1) * 2;
        int half = blk & 1;
        int rg   = tid >> 4;    // 16 f-rows in flight
        int l    = tid & 15;
#pragma unroll 2
        for (int p = 0; p < 8; ++p) {
            int f = half * 128 + p * 16 + rg;
            float4 fv0 = ((const float4*)(feature + ((size_t)(b0 * F + f)) * D))[l];
            float4 fv1 = ((const float4*)(feature + ((size_t)((b0 + 1) * F + f)) * D))[l];
            float4 q0 = ((const float4*)(qkv + f * D))[l];
            float4 q1 = ((const float4*)(qkv + F * D + f * D))[l];
            float4 q2 = ((const float4*)(qkv + 2 * F * D + f * D))[l];
            float a00 = dot4(fv0, q0);
            float a01 = dot4(fv0, q1);
            float a02 = dot4(fv0, q2);
            float a10 = dot4(fv1, q0);
            float a11 = dot4(fv1, q1);
            float a12 = dot4(fv1, q2);
#pragma unroll
            for (int m = 1; m < 16; m <<= 1) {
                a00 += __shfl_xor(a00, m, 64);
                a01 += __shfl_xor(a01, m, 64);
                a02 += __shfl_xor(a02, m, 64);
                a10 += __shfl_xor(a10, m, 64);
                a11 += __shfl_xor(a11, m, 64);
                a12 += __shfl_xor(a12, m, 64);
            }
            if (l == 0) {
                gS[b0 * F + f]        = a00 * a02;
                gS[(b0 + 1) * F + f]  = a10 * a12;
                s1S[b0 * F + f]       = f2bf(a01);
                s1S[(b0 + 1) * F + f] = f2bf(a11);
            }
        }
    } else {
        // ---- compute_Mt: At[(j>>5)][i][j&31] = gate(i,j) ? qkv1[i].qkv0[j] : 0
        //      q2K[(i>>5)][p(j)][i&31] = qkv2[i][j], p(j)=(j&3)*16+(j>>2) ----
        int j = blk - B;   // F columns
        int i = tid;       // F threads
        const float4* t0 = (const float4*)(trans + i * D);
        const float4* t1 = (const float4*)(trans + F * D + j * D);
        const float4* q1 = (const float4*)(qkv + F * D + i * D);
        const float4* q0 = (const float4*)(qkv + j * D);
        float d0 = 0.f, d1 = 0.f;
#pragma unroll 2
        for (int k = 0; k < D / 4; ++k) {
            float4 a = t0[k], b = t1[k], c = q1[k], e = q0[k];
            d0 += dot4(a, b);
            d1 += dot4(c, e);
        }
        float v = (d0 > 0.f) ? d1 : 0.f;
        At[((j >> 5) * F + i) * 32 + (j & 31)] = f2bf(v);
        if (j < D) {
            int p = (j & 3) * 16 + (j >> 2);   // d-permutation for float4 stores
            q2K[((i >> 5) * D + p) * 32 + (i & 31)] = f2bf(qkv[2 * F * D + i * D + j]);
        }
    }
}

// Kernel G (round-5 bf16 version, known-good):
// out[b,i,d] = gS[b,i] * sum_j At[i,j] * s1[b,j] * q2[j,d]
// Block = (batch-group of 8, i-tile of 64 rows); 512 threads / 8 waves.
// At i-slice (32 KB) + q2K (32 KB) staged ONCE into LDS.
// B-fragment nt at lane l16 holds logical d-col l16*4+nt (via q2K permutation)
// -> epilogue is float4 (dwordx4) stores, 16 B/lane.
__global__ __launch_bounds__(512, 4) void gemm_out(const short* __restrict__ At,
                                                   const short* __restrict__ q2K,
                                                   const float* __restrict__ gS,
                                                   const short* __restrict__ s1S,
                                                   float* __restrict__ out) {
    int it  = blockIdx.x & 3;        // i-tile: rows [it*64, it*64+64)
    int bg  = blockIdx.x >> 2;       // batch-group of 8
    int tid = threadIdx.x;

    __shared__ __align__(16) short AtL[8 * 64 * 32];   // 32 KB: [jt][row 0..63][32]
    __shared__ __align__(16) short q2L[8 * 64 * 32];   // 32 KB: [jt][slot 0..63][32]

    // ---- stage At i-slice + q2K into LDS (coalesced float4 copies) ----
    {
        const float4* Ag = (const float4*)At;
        const float4* Qg = (const float4*)q2K;
        float4* Al = (float4*)AtL;
        float4* Ql = (float4*)q2L;
#pragma unroll
        for (int v = tid; v < 2048; v += 512) {
            int jt = v >> 8, k = v & 255;                 // 256 float4 per jt-chunk
            Al[v] = Ag[jt * 1024 + it * 256 + k];         // global chunk stride = 1024 f4
        }
#pragma unroll
        for (int v = tid; v < 2048; v += 512) Ql[v] = Qg[v];
    }
    __syncthreads();

    int w    = tid >> 6;        // wave -> batch
    int lane = tid & 63;
    int l16  = lane & 15;
    int lq   = lane >> 4;
    int kq   = lq * 8;
    int b    = bg * 8 + w;

    const short* s1b = s1S + b * F;

    f32x4 acc[4][4];
#pragma unroll
    for (int mt = 0; mt < 4; ++mt)
#pragma unroll
        for (int nt = 0; nt < 4; ++nt) acc[mt][nt] = (f32x4){0.f, 0.f, 0.f, 0.f};

    for (int jt = 0; jt < F / 32; ++jt) {
        // s1 fragment (broadcast within 16-lane groups): 8 bf16 -> f32
        short8 sv = *(const short8*)(s1b + jt * 32 + kq);
        float sf[8];
#pragma unroll
        for (int e = 0; e < 8; ++e) sf[e] = bf2f(sv[e]);

        // B fragments from LDS: q2 physical slot nt*16+l16 (logical d=l16*4+nt),
        // scaled by s1, packed bf16
        short8 bfr[4];
#pragma unroll
        for (int nt = 0; nt < 4; ++nt) {
            int d = nt * 16 + l16;
            short8 qv = *(const short8*)(q2L + (jt * 64 + d) * 32 + kq);
            int4 packed;
            packed.x = pk_bf16(bf2f(qv[0]) * sf[0], bf2f(qv[1]) * sf[1]);
            packed.y = pk_bf16(bf2f(qv[2]) * sf[2], bf2f(qv[3]) * sf[3]);
            packed.z = pk_bf16(bf2f(qv[4]) * sf[4], bf2f(qv[5]) * sf[5]);
            packed.w = pk_bf16(bf2f(qv[6]) * sf[6], bf2f(qv[7]) * sf[7]);
            bfr[nt] = __builtin_bit_cast(short8, packed);
        }
        // A fragments from LDS + MFMA over the 64-row i-tile
#pragma unroll
        for (int mt = 0; mt < 4; ++mt) {
            short8 af = *(const short8*)(AtL + (jt * 64 + mt * 16 + l16) * 32 + kq);
#pragma unroll
            for (int nt = 0; nt < 4; ++nt)
                acc[mt][nt] = __builtin_amdgcn_mfma_f32_16x16x32_bf16(
                    af, bfr[nt], acc[mt][nt], 0, 0, 0);
        }
    }

    // ---- epilogue: gS row scale + float4 stores (cols l16*4 .. l16*4+3) ----
    const float4* g4 = (const float4*)(gS + b * F + it * 64);
#pragma unroll
    for (int mt = 0; mt < 4; ++mt) {
        float4 gg = g4[mt * 4 + lq];   // rows it*64 + mt*16 + lq*4 .. +3
        float* obase = out + ((size_t)(b * F + it * 64 + mt * 16 + lq * 4)) * D + l16 * 4;
        float4 v0 = {gg.x * acc[mt][0][0], gg.x * acc[mt][1][0],
                     gg.x * acc[mt][2][0], gg.x * acc[mt][3][0]};
        float4 v1 = {gg.y * acc[mt][0][1], gg.y * acc[mt][1][1],
                     gg.y * acc[mt][2][1], gg.y * acc[mt][3][1]};
        float4 v2 = {gg.z * acc[mt][0][2], gg.z * acc[mt][1][2],
                     gg.z * acc[mt][2][2], gg.z * acc[mt][3][2]};
        float4 v3 = {gg.w * acc[mt][0][3], gg.w * acc[mt][1][3],
                     gg.w * acc[mt][2][3], gg.w * acc[mt][3][3]};
        *(float4*)(obase + 0 * D) = v0;
        *(float4*)(obase + 1 * D) = v1;
        *(float4*)(obase + 2 * D) = v2;
        *(float4*)(obase + 3 * D) = v3;
    }
}

extern "C" void kernel_launch(void* const* d_in, const int* in_sizes, int n_in,
                              void* d_out, int out_size, void* d_ws, size_t ws_size,
                              hipStream_t stream) {
    const float* feature   = (const float*)d_in[0];
    const float* indicator = (const float*)d_in[1];
    const float* W_qk      = (const float*)d_in[2];
    const float* W_qkv     = (const float*)d_in[3];
    float* out = (float*)d_out;

    float* ws    = (float*)d_ws;
    float* trans = ws;                        // 2*F*D f32
    float* qkv   = trans + 2 * F * D;         // 3*F*D f32
    float* gS    = qkv + 3 * F * D;           // B*F f32
    short* At    = (short*)(gS + B * F);      // F*F bf16 (K-tiled)
    short* q2K   = At + F * F;                // (F/32)*64*32 bf16 (K-tiled, permuted)
    short* s1S   = q2K + (F / 32) * D * 32;   // B*F bf16

    hipLaunchKernelGGL(precompute_trans, dim3((5 * F * D) / 256), dim3(256), 0,
                       stream, indicator, W_qk, W_qkv, trans, qkv);
    hipLaunchKernelGGL(s_and_Mt, dim3(B + F), dim3(256), 0, stream,
                       feature, trans, qkv, gS, s1S, At, q2K);
    hipLaunchKernelGGL(gemm_out, dim3((B / 8) * 4), dim3(512), 0, stream,
                       At, q2K, gS, s1S, out);
}